// Round 5
// baseline (110.614 us; speedup 1.0000x reference)
//
#include <hip/hip_runtime.h>
#include <hip/hip_bf16.h>
#include <hip/hip_fp16.h>

#define FM_N 4
#define FM_C 256
#define FM_H 200
#define FM_W 200
#define CROP_H 14
#define CROP_W 14
#define HW 196
#define M_BOXES 512
#define NSAMP (M_BOXES * HW)      // 100352
#define NROWS (M_BOXES * CROP_H)  // 7168
#define PLANE (FM_H * FM_W)       // 40000
#define OUT_CH_STRIDE (FM_C * HW) // 50176
#define NOCT 8
#define OCT_ROWS 25
#define STAGE_ROWS 26             // h<7 stages 26 rows, h==7 stages 25
#define K3_LDS (STAGE_ROWS * FM_W * 8)  // 41600 B: [pixel][4ch] f16
#define NBIN (FM_N * NOCT)        // 32

// ws layout
#define WS_ROWBIN   0             // u8[7168]
#define WS_ROWRANK  8192          // i32[7168] -> ends 36864
#define WS_COUNTS   36864         // i32[32]
#define WS_BASES    36992         // i32[32]
#define WS_RECS     40960         // uint4[NSAMP] (16 B records)
#define WS_NEED     (WS_RECS + (size_t)NSAMP * 16)

__device__ __forceinline__ unsigned pack2h(float a, float b) {
    unsigned lo = (unsigned)__half_as_ushort(__float2half_rn(a));
    unsigned hi = (unsigned)__half_as_ushort(__float2half_rn(b));
    return lo | (hi << 16);
}
__device__ __forceinline__ float cvlo(unsigned u) {
    __half2 h = __builtin_bit_cast(__half2, u); return __low2float(h);
}
__device__ __forceinline__ float cvhi(unsigned u) {
    __half2 h = __builtin_bit_cast(__half2, u); return __high2float(h);
}

// Bit-identical py across kernels: explicit intrinsics, no contraction freedom.
__device__ __forceinline__ float row_py(const float* __restrict__ boxes, int m, int i) {
    float y1 = boxes[4 * m + 1], y2 = boxes[4 * m + 3];
    float sh  = __fmul_rn(__fsub_rn(y2, y1), 1.0f / 14.0f);
    float t   = __fsub_rn(__fadd_rn(y1, __fmul_rn(sh, 0.5f)), 0.5f);
    float ny0 = __fmul_rn(t, 1.0f / 199.0f);
    float nh  = __fmul_rn(sh, 13.0f / 199.0f);
    float gy  = __fmul_rn((float)i, 1.0f / 13.0f);
    return __fmul_rn(__fadd_rn(ny0, __fmul_rn(nh, gy)), 199.0f);
}

// ---------- K1: fused rowbin + deterministic rank-within-bin + counts/bases ----------
__global__ __launch_bounds__(1024) void k1_binscan(
    const float* __restrict__ boxes, const int* __restrict__ box_ind,
    unsigned char* __restrict__ rowbin, int* __restrict__ rowrank,
    int* __restrict__ counts, int* __restrict__ bases)
{
    __shared__ int scnt[NBIN];
    __shared__ int sbase[NBIN];
    int tid = threadIdx.x;
    int w = tid >> 6, lane = tid & 63;
    unsigned long long lm = (1ull << lane) - 1ull;  // lane 63 -> 0x7fff... (correct)
    const int b0 = w, b1 = w + 16;
    int cnt0 = 0, cnt1 = 0;
    for (int k = 0; k < NROWS; k += 64) {
        int r = k + lane;
        int m = r / CROP_H, i = r - m * CROP_H;
        float py = row_py(boxes, m, i);
        int y0c = min(max((int)floorf(py), 0), FM_H - 1);
        int bin = box_ind[m] * NOCT + y0c / OCT_ROWS;   // y0c/25 <= 7
        if (w == 0) rowbin[r] = (unsigned char)bin;
        bool m0 = (bin == b0);
        unsigned long long bal0 = __ballot(m0);
        if (m0) rowrank[r] = cnt0 + (int)__popcll(bal0 & lm);
        cnt0 += (int)__popcll(bal0);
        bool m1 = (bin == b1);
        unsigned long long bal1 = __ballot(m1);
        if (m1) rowrank[r] = cnt1 + (int)__popcll(bal1 & lm);
        cnt1 += (int)__popcll(bal1);
    }
    if (lane == 0) { scnt[b0] = cnt0; scnt[b1] = cnt1; }
    __syncthreads();
    if (tid == 0) {
        int acc = 0;
        for (int q = 0; q < NBIN; ++q) { sbase[q] = acc; acc += scnt[q]; }
    }
    __syncthreads();
    if (tid < NBIN) { counts[tid] = scnt[tid]; bases[tid] = sbase[tid]; }
}

// ---------- K2: 16-B per-sample records, ordered by (bin, row-rank, j) ----------
__global__ __launch_bounds__(256) void k2_records(
    const float* __restrict__ boxes,
    const unsigned char* __restrict__ rowbin, const int* __restrict__ rowrank,
    const int* __restrict__ bases, uint4* __restrict__ recs)
{
    int g = blockIdx.x * 256 + threadIdx.x;
    if (g >= NSAMP) return;
    int m  = g / HW;
    int ij = g - m * HW;
    int i  = ij / CROP_W;
    int j  = ij - i * CROP_W;

    float x1 = boxes[4 * m + 0], x2 = boxes[4 * m + 2];

    float sw  = (x2 - x1) / (float)CROP_W;
    float nx0 = (x1 + sw * 0.5f - 0.5f) / 199.0f;
    float nw  = sw * 13.0f / 199.0f;
    float px  = (nx0 + nw * ((float)j * (1.0f / 13.0f))) * 199.0f;

    float py = row_py(boxes, m, i);

    float y0f = floorf(py), x0f = floorf(px);
    float wy = py - y0f, wx = px - x0f;
    int y0 = (int)y0f, x0 = (int)x0f;
    int y1i = y0 + 1, x1i = x0 + 1;

    float v00 = (y0  >= 0 && y0  < FM_H && x0  >= 0 && x0  < FM_W) ? 1.0f : 0.0f;
    float v01 = (y0  >= 0 && y0  < FM_H && x1i >= 0 && x1i < FM_W) ? 1.0f : 0.0f;
    float v10 = (y1i >= 0 && y1i < FM_H && x0  >= 0 && x0  < FM_W) ? 1.0f : 0.0f;
    float v11 = (y1i >= 0 && y1i < FM_H && x1i >= 0 && x1i < FM_W) ? 1.0f : 0.0f;

    float w00 = (1.0f - wy) * (1.0f - wx) * v00;
    float w01 = (1.0f - wy) * wx          * v01;
    float w10 = wy          * (1.0f - wx) * v10;
    float w11 = wy          * wx          * v11;

    int y0c = min(max(y0,  0), FM_H - 1);
    int y1c = min(max(y1i, 0), FM_H - 1);
    int x0c = min(max(x0,  0), FM_W - 1);
    int x1c = min(max(x1i, 0), FM_W - 1);
    int dx  = x1c - x0c;                 // 0 or 1

    int row = m * CROP_H + i;
    int bin = rowbin[row];
    int h   = bin & 7;
    // defensive clamp to staged range [0, STAGE_ROWS-1]
    int ly0 = min(max(y0c - h * OCT_ROWS, 0), STAGE_ROWS - 1);
    int ly1 = min(max(y1c - h * OCT_ROWS, 0), STAGE_ROWS - 1);

    unsigned o00 = (unsigned)(ly0 * FM_W + x0c);   // <= 5199
    unsigned o10 = (unsigned)(ly1 * FM_W + x0c);

    int slot = (bases[bin] + rowrank[row]) * CROP_W + j;
    unsigned outw = (unsigned)(m * OUT_CH_STRIDE + ij);

    recs[slot] = make_uint4(pack2h(w00, w01), pack2h(w10, w11),
                            o00 | (o10 << 16),
                            outw | ((unsigned)dx << 31));
}

// ---------- K3: stage 26-row x 4ch interleaved f16 octant, pipelined gather ----------
__global__ __launch_bounds__(512) void k3_main(
    const float* __restrict__ fm, const uint4* __restrict__ recs,
    const int* __restrict__ counts, const int* __restrict__ bases,
    float* __restrict__ out)
{
    extern __shared__ char smem[];
    const int bid  = blockIdx.x;
    const int quad = bid & 63;
    const int h    = (bid >> 6) & 7;
    const int n    = bid >> 9;
    const int tid  = threadIdx.x;
    const int bin  = n * NOCT + h;

    const int cnt = counts[bin];
    if (cnt == 0) return;                 // uniform early-out (before barrier)

    const int rows = (h == 7) ? 25 : 26;
    const int ngrp = rows * (FM_W / 4);   // float4 groups per plane
    const float* p0 = fm + (size_t)(n * FM_C + quad * 4) * PLANE + h * OCT_ROWS * FM_W;

    for (int t = tid; t < ngrp; t += 512) {
        int px = t * 4;
        float4 a = *(const float4*)(p0 + px);
        float4 b = *(const float4*)(p0 + PLANE + px);
        float4 c = *(const float4*)(p0 + 2 * PLANE + px);
        float4 d = *(const float4*)(p0 + 3 * PLANE + px);
        uint4 w0, w1;
        w0.x = pack2h(a.x, b.x); w0.y = pack2h(c.x, d.x);
        w0.z = pack2h(a.y, b.y); w0.w = pack2h(c.y, d.y);
        w1.x = pack2h(a.z, b.z); w1.y = pack2h(c.z, d.z);
        w1.z = pack2h(a.w, b.w); w1.w = pack2h(c.w, d.w);
        *(uint4*)(smem + (size_t)px * 8)      = w0;
        *(uint4*)(smem + (size_t)px * 8 + 16) = w1;
    }
    __syncthreads();

    const int T = cnt * CROP_W;
    const uint4* rp = recs + (size_t)bases[bin] * CROP_W;
    float* outq = out + quad * 4 * HW;

    int s = tid;
    if (s >= T) return;
    uint4 r = rp[s];
    while (true) {
        int sn = s + 512;
        bool more = sn < T;
        uint4 rn = r;
        if (more) rn = rp[sn];            // prefetch next record

        float w00 = cvlo(r.x), w01 = cvhi(r.x);
        float w10 = cvlo(r.y), w11 = cvhi(r.y);
        unsigned o00 = r.z & 0xffffu, o10 = r.z >> 16;
        unsigned dx  = r.w >> 31;
        unsigned ow  = r.w & 0x7fffffffu;

        uint2 t00 = *(const uint2*)(smem + (size_t)o00 * 8);
        uint2 t01 = *(const uint2*)(smem + (size_t)(o00 + dx) * 8);
        uint2 t10 = *(const uint2*)(smem + (size_t)o10 * 8);
        uint2 t11 = *(const uint2*)(smem + (size_t)(o10 + dx) * 8);

        float r0 = cvlo(t00.x) * w00 + cvlo(t01.x) * w01 + cvlo(t10.x) * w10 + cvlo(t11.x) * w11;
        float r1 = cvhi(t00.x) * w00 + cvhi(t01.x) * w01 + cvhi(t10.x) * w10 + cvhi(t11.x) * w11;
        float r2 = cvlo(t00.y) * w00 + cvlo(t01.y) * w01 + cvlo(t10.y) * w10 + cvlo(t11.y) * w11;
        float r3 = cvhi(t00.y) * w00 + cvhi(t01.y) * w01 + cvhi(t10.y) * w10 + cvhi(t11.y) * w11;

        float* op = outq + ow;
        __builtin_nontemporal_store(r0, op);
        __builtin_nontemporal_store(r1, op + HW);
        __builtin_nontemporal_store(r2, op + 2 * HW);
        __builtin_nontemporal_store(r3, op + 3 * HW);

        if (!more) break;
        r = rn; s = sn;
    }
}

// ---------- fallback (round-2 kernel) if workspace too small ----------
#define CH_PER_THREAD 8
#define GROUPS (FM_C / CH_PER_THREAD)
__global__ __launch_bounds__(256) void roi_fallback_kernel(
    const float* __restrict__ fm, const float* __restrict__ boxes,
    const int* __restrict__ box_ind, float* __restrict__ out, int total)
{
    int idx = blockIdx.x * blockDim.x + threadIdx.x;
    if (idx >= total) return;
    int ij = idx % HW;
    int t  = idx / HW;
    int cg = t % GROUPS;
    int m  = t / GROUPS;
    int i  = ij / CROP_W;
    int j  = ij % CROP_W;
    float x1 = boxes[4*m+0], y1 = boxes[4*m+1], x2 = boxes[4*m+2], y2 = boxes[4*m+3];
    int b = box_ind[m];
    float sw = (x2-x1)/(float)CROP_W, sh = (y2-y1)/(float)CROP_H;
    float nx0 = (x1 + sw*0.5f - 0.5f)/199.f;
    float ny0 = (y1 + sh*0.5f - 0.5f)/199.f;
    float nw = sw*13.f/199.f, nh = sh*13.f/199.f;
    float py = (ny0 + nh*((float)i*(1.0f/13.0f)))*199.f;
    float px = (nx0 + nw*((float)j*(1.0f/13.0f)))*199.f;
    float y0f = floorf(py), x0f = floorf(px);
    float wy = py-y0f, wx = px-x0f;
    int y0 = (int)y0f, x0 = (int)x0f, y1i = y0+1, x1i = x0+1;
    float v00 = (y0>=0 && y0<FM_H && x0>=0 && x0<FM_W) ? 1.f : 0.f;
    float v01 = (y0>=0 && y0<FM_H && x1i>=0 && x1i<FM_W) ? 1.f : 0.f;
    float v10 = (y1i>=0 && y1i<FM_H && x0>=0 && x0<FM_W) ? 1.f : 0.f;
    float v11 = (y1i>=0 && y1i<FM_H && x1i>=0 && x1i<FM_W) ? 1.f : 0.f;
    float w00 = (1.f-wy)*(1.f-wx)*v00, w01 = (1.f-wy)*wx*v01;
    float w10 = wy*(1.f-wx)*v10, w11 = wy*wx*v11;
    int y0c = min(max(y0,0),FM_H-1), y1c = min(max(y1i,0),FM_H-1);
    int x0c = min(max(x0,0),FM_W-1), x1c = min(max(x1i,0),FM_W-1);
    unsigned base = ((unsigned)b*FM_C + (unsigned)(cg*CH_PER_THREAD))*PLANE;
    unsigned o00 = base + (unsigned)(y0c*FM_W+x0c);
    unsigned o01 = base + (unsigned)(y0c*FM_W+x1c);
    unsigned o10 = base + (unsigned)(y1c*FM_W+x0c);
    unsigned o11 = base + (unsigned)(y1c*FM_W+x1c);
    float* outp = out + (size_t)(m*FM_C + cg*CH_PER_THREAD)*HW + ij;
#pragma unroll
    for (int k = 0; k < CH_PER_THREAD; ++k) {
        float r = fm[o00]*w00 + fm[o01]*w01 + fm[o10]*w10 + fm[o11]*w11;
        __builtin_nontemporal_store(r, outp);
        o00 += PLANE; o01 += PLANE; o10 += PLANE; o11 += PLANE;
        outp += HW;
    }
}

extern "C" void kernel_launch(void* const* d_in, const int* in_sizes, int n_in,
                              void* d_out, int out_size, void* d_ws, size_t ws_size,
                              hipStream_t stream) {
    const float* fm      = (const float*)d_in[0];
    const float* boxes   = (const float*)d_in[1];
    const int*   box_ind = (const int*)d_in[2];
    float* out = (float*)d_out;

    if (ws_size < WS_NEED) {
        int total = out_size / CH_PER_THREAD;
        int grid = (total + 255) / 256;
        roi_fallback_kernel<<<grid, 256, 0, stream>>>(fm, boxes, box_ind, out, total);
        return;
    }

    unsigned char* rowbin = (unsigned char*)d_ws + WS_ROWBIN;
    int*   rowrank = (int*)((char*)d_ws + WS_ROWRANK);
    int*   counts  = (int*)((char*)d_ws + WS_COUNTS);
    int*   bases   = (int*)((char*)d_ws + WS_BASES);
    uint4* recs    = (uint4*)((char*)d_ws + WS_RECS);

    k1_binscan<<<1, 1024, 0, stream>>>(boxes, box_ind, rowbin, rowrank, counts, bases);
    k2_records<<<NSAMP / 256, 256, 0, stream>>>(boxes, rowbin, rowrank, bases, recs);

    hipFuncSetAttribute((const void*)k3_main,
                        hipFuncAttributeMaxDynamicSharedMemorySize, K3_LDS);
    k3_main<<<FM_N * NOCT * 64, 512, K3_LDS, stream>>>(fm, recs, counts, bases, out);
}

// Round 6
// 104.037 us; speedup vs baseline: 1.0632x; 1.0632x over previous
//
#include <hip/hip_runtime.h>
#include <hip/hip_bf16.h>
#include <hip/hip_fp16.h>

#define FM_N 4
#define FM_C 256
#define FM_H 200
#define FM_W 200
#define CROP_H 14
#define CROP_W 14
#define HW 196
#define M_BOXES 512
#define NSAMP (M_BOXES * HW)      // 100352
#define NROWS (M_BOXES * CROP_H)  // 7168
#define PLANE (FM_H * FM_W)       // 40000
#define OUT_CH_STRIDE (FM_C * HW) // 50176
#define NOCT 8
#define OCT_ROWS 25
#define STAGE_ROWS 26             // h<7 stages 26 rows, h==7 stages 25
#define K3_LDS (STAGE_ROWS * FM_W * 8)  // 41600 B: [pixel][4ch] f16
#define NBIN (FM_N * NOCT)        // 32

// ws layout
#define WS_ROWBIN   0             // u8[7168]
#define WS_ROWRANK  8192          // i32[7168] -> ends 36864
#define WS_COUNTS   36864         // i32[32]
#define WS_BASES    36992         // i32[32]
#define WS_RECS     40960         // uint4[NSAMP] (16 B records)
#define WS_NEED     (WS_RECS + (size_t)NSAMP * 16)

__device__ __forceinline__ unsigned pack2h(float a, float b) {
    unsigned lo = (unsigned)__half_as_ushort(__float2half_rn(a));
    unsigned hi = (unsigned)__half_as_ushort(__float2half_rn(b));
    return lo | (hi << 16);
}
__device__ __forceinline__ float cvlo(unsigned u) {
    __half2 h = __builtin_bit_cast(__half2, u); return __low2float(h);
}
__device__ __forceinline__ float cvhi(unsigned u) {
    __half2 h = __builtin_bit_cast(__half2, u); return __high2float(h);
}

// Bit-identical py across kernels: explicit intrinsics, no contraction freedom.
__device__ __forceinline__ float row_py(const float* __restrict__ boxes, int m, int i) {
    float y1 = boxes[4 * m + 1], y2 = boxes[4 * m + 3];
    float sh  = __fmul_rn(__fsub_rn(y2, y1), 1.0f / 14.0f);
    float t   = __fsub_rn(__fadd_rn(y1, __fmul_rn(sh, 0.5f)), 0.5f);
    float ny0 = __fmul_rn(t, 1.0f / 199.0f);
    float nh  = __fmul_rn(sh, 13.0f / 199.0f);
    float gy  = __fmul_rn((float)i, 1.0f / 13.0f);
    return __fmul_rn(__fadd_rn(ny0, __fmul_rn(nh, gy)), 199.0f);
}

// ---------- K1: fused rowbin + deterministic rank-within-bin + counts/bases ----------
__global__ __launch_bounds__(1024) void k1_binscan(
    const float* __restrict__ boxes, const int* __restrict__ box_ind,
    unsigned char* __restrict__ rowbin, int* __restrict__ rowrank,
    int* __restrict__ counts, int* __restrict__ bases)
{
    __shared__ int scnt[NBIN];
    __shared__ int sbase[NBIN];
    int tid = threadIdx.x;
    int w = tid >> 6, lane = tid & 63;
    unsigned long long lm = (1ull << lane) - 1ull;
    const int b0 = w, b1 = w + 16;
    int cnt0 = 0, cnt1 = 0;
    for (int k = 0; k < NROWS; k += 64) {
        int r = k + lane;
        int m = r / CROP_H, i = r - m * CROP_H;
        float py = row_py(boxes, m, i);
        int y0c = min(max((int)floorf(py), 0), FM_H - 1);
        int bin = box_ind[m] * NOCT + y0c / OCT_ROWS;   // y0c/25 <= 7
        if (w == 0) rowbin[r] = (unsigned char)bin;
        bool m0 = (bin == b0);
        unsigned long long bal0 = __ballot(m0);
        if (m0) rowrank[r] = cnt0 + (int)__popcll(bal0 & lm);
        cnt0 += (int)__popcll(bal0);
        bool m1 = (bin == b1);
        unsigned long long bal1 = __ballot(m1);
        if (m1) rowrank[r] = cnt1 + (int)__popcll(bal1 & lm);
        cnt1 += (int)__popcll(bal1);
    }
    if (lane == 0) { scnt[b0] = cnt0; scnt[b1] = cnt1; }
    __syncthreads();
    if (tid == 0) {
        int acc = 0;
        for (int q = 0; q < NBIN; ++q) { sbase[q] = acc; acc += scnt[q]; }
    }
    __syncthreads();
    if (tid < NBIN) { counts[tid] = scnt[tid]; bases[tid] = sbase[tid]; }
}

// ---------- K2: 16-B per-sample records, ordered by (bin, row-rank, j) ----------
__global__ __launch_bounds__(256) void k2_records(
    const float* __restrict__ boxes,
    const unsigned char* __restrict__ rowbin, const int* __restrict__ rowrank,
    const int* __restrict__ bases, uint4* __restrict__ recs)
{
    int g = blockIdx.x * 256 + threadIdx.x;
    if (g >= NSAMP) return;
    int m  = g / HW;
    int ij = g - m * HW;
    int i  = ij / CROP_W;
    int j  = ij - i * CROP_W;

    float x1 = boxes[4 * m + 0], x2 = boxes[4 * m + 2];

    float sw  = (x2 - x1) / (float)CROP_W;
    float nx0 = (x1 + sw * 0.5f - 0.5f) / 199.0f;
    float nw  = sw * 13.0f / 199.0f;
    float px  = (nx0 + nw * ((float)j * (1.0f / 13.0f))) * 199.0f;

    float py = row_py(boxes, m, i);

    float y0f = floorf(py), x0f = floorf(px);
    float wy = py - y0f, wx = px - x0f;
    int y0 = (int)y0f, x0 = (int)x0f;
    int y1i = y0 + 1, x1i = x0 + 1;

    float v00 = (y0  >= 0 && y0  < FM_H && x0  >= 0 && x0  < FM_W) ? 1.0f : 0.0f;
    float v01 = (y0  >= 0 && y0  < FM_H && x1i >= 0 && x1i < FM_W) ? 1.0f : 0.0f;
    float v10 = (y1i >= 0 && y1i < FM_H && x0  >= 0 && x0  < FM_W) ? 1.0f : 0.0f;
    float v11 = (y1i >= 0 && y1i < FM_H && x1i >= 0 && x1i < FM_W) ? 1.0f : 0.0f;

    float w00 = (1.0f - wy) * (1.0f - wx) * v00;
    float w01 = (1.0f - wy) * wx          * v01;
    float w10 = wy          * (1.0f - wx) * v10;
    float w11 = wy          * wx          * v11;

    int y0c = min(max(y0,  0), FM_H - 1);
    int y1c = min(max(y1i, 0), FM_H - 1);
    int x0c = min(max(x0,  0), FM_W - 1);
    int x1c = min(max(x1i, 0), FM_W - 1);
    int dx  = x1c - x0c;                 // 0 or 1

    int row = m * CROP_H + i;
    int bin = rowbin[row];
    int h   = bin & 7;
    // defensive clamp to staged range [0, STAGE_ROWS-1]
    int ly0 = min(max(y0c - h * OCT_ROWS, 0), STAGE_ROWS - 1);
    int ly1 = min(max(y1c - h * OCT_ROWS, 0), STAGE_ROWS - 1);

    unsigned o00 = (unsigned)(ly0 * FM_W + x0c);   // <= 5199
    unsigned o10 = (unsigned)(ly1 * FM_W + x0c);

    int slot = (bases[bin] + rowrank[row]) * CROP_W + j;
    unsigned outw = (unsigned)(m * OUT_CH_STRIDE + ij);

    recs[slot] = make_uint4(pack2h(w00, w01), pack2h(w10, w11),
                            o00 | (o10 << 16),
                            outw | ((unsigned)dx << 31));
}

// ---------- K3: stage 26-row x 4ch interleaved f16 octant, pipelined gather ----------
__global__ __launch_bounds__(512) void k3_main(
    const float* __restrict__ fm, const uint4* __restrict__ recs,
    const int* __restrict__ counts, const int* __restrict__ bases,
    float* __restrict__ out)
{
    extern __shared__ char smem[];
    const int bid  = blockIdx.x;
    const int quad = bid & 63;
    const int h    = (bid >> 6) & 7;
    const int n    = bid >> 9;
    const int tid  = threadIdx.x;
    const int bin  = n * NOCT + h;

    const int cnt = counts[bin];
    if (cnt == 0) return;                 // uniform early-out (before barrier)

    const int rows = (h == 7) ? 25 : 26;
    const int ngrp = rows * (FM_W / 4);   // float4 groups per plane
    const float* p0 = fm + (size_t)(n * FM_C + quad * 4) * PLANE + h * OCT_ROWS * FM_W;

    for (int t = tid; t < ngrp; t += 512) {
        int px = t * 4;
        float4 a = *(const float4*)(p0 + px);
        float4 b = *(const float4*)(p0 + PLANE + px);
        float4 c = *(const float4*)(p0 + 2 * PLANE + px);
        float4 d = *(const float4*)(p0 + 3 * PLANE + px);
        uint4 w0, w1;
        w0.x = pack2h(a.x, b.x); w0.y = pack2h(c.x, d.x);
        w0.z = pack2h(a.y, b.y); w0.w = pack2h(c.y, d.y);
        w1.x = pack2h(a.z, b.z); w1.y = pack2h(c.z, d.z);
        w1.z = pack2h(a.w, b.w); w1.w = pack2h(c.w, d.w);
        *(uint4*)(smem + (size_t)px * 8)      = w0;
        *(uint4*)(smem + (size_t)px * 8 + 16) = w1;
    }
    __syncthreads();

    const int T = cnt * CROP_W;
    const uint4* rp = recs + (size_t)bases[bin] * CROP_W;
    float* outq = out + quad * 4 * HW;

    int s = tid;
    if (s >= T) return;
    uint4 r = rp[s];
    while (true) {
        int sn = s + 512;
        bool more = sn < T;
        uint4 rn = r;
        if (more) rn = rp[sn];            // prefetch next record

        float w00 = cvlo(r.x), w01 = cvhi(r.x);
        float w10 = cvlo(r.y), w11 = cvhi(r.y);
        unsigned o00 = r.z & 0xffffu, o10 = r.z >> 16;
        unsigned dx  = r.w >> 31;
        unsigned ow  = r.w & 0x7fffffffu;

        uint2 t00 = *(const uint2*)(smem + (size_t)o00 * 8);
        uint2 t01 = *(const uint2*)(smem + (size_t)(o00 + dx) * 8);
        uint2 t10 = *(const uint2*)(smem + (size_t)o10 * 8);
        uint2 t11 = *(const uint2*)(smem + (size_t)(o10 + dx) * 8);

        float r0 = cvlo(t00.x) * w00 + cvlo(t01.x) * w01 + cvlo(t10.x) * w10 + cvlo(t11.x) * w11;
        float r1 = cvhi(t00.x) * w00 + cvhi(t01.x) * w01 + cvhi(t10.x) * w10 + cvhi(t11.x) * w11;
        float r2 = cvlo(t00.y) * w00 + cvlo(t01.y) * w01 + cvlo(t10.y) * w10 + cvlo(t11.y) * w11;
        float r3 = cvhi(t00.y) * w00 + cvhi(t01.y) * w01 + cvhi(t10.y) * w10 + cvhi(t11.y) * w11;

        // Plain cached stores: partial crop-row runs (14 dwords) merge to full
        // 64-B lines in L2 before writeback. NT here forced sub-line HBM RMW
        // (the ~110 us wall of rounds 3-5).
        float* op = outq + ow;
        op[0]      = r0;
        op[HW]     = r1;
        op[2 * HW] = r2;
        op[3 * HW] = r3;

        if (!more) break;
        r = rn; s = sn;
    }
}

// ---------- fallback (round-2 kernel) if workspace too small ----------
#define CH_PER_THREAD 8
#define GROUPS (FM_C / CH_PER_THREAD)
__global__ __launch_bounds__(256) void roi_fallback_kernel(
    const float* __restrict__ fm, const float* __restrict__ boxes,
    const int* __restrict__ box_ind, float* __restrict__ out, int total)
{
    int idx = blockIdx.x * blockDim.x + threadIdx.x;
    if (idx >= total) return;
    int ij = idx % HW;
    int t  = idx / HW;
    int cg = t % GROUPS;
    int m  = t / GROUPS;
    int i  = ij / CROP_W;
    int j  = ij % CROP_W;
    float x1 = boxes[4*m+0], y1 = boxes[4*m+1], x2 = boxes[4*m+2], y2 = boxes[4*m+3];
    int b = box_ind[m];
    float sw = (x2-x1)/(float)CROP_W, sh = (y2-y1)/(float)CROP_H;
    float nx0 = (x1 + sw*0.5f - 0.5f)/199.f;
    float ny0 = (y1 + sh*0.5f - 0.5f)/199.f;
    float nw = sw*13.f/199.f, nh = sh*13.f/199.f;
    float py = (ny0 + nh*((float)i*(1.0f/13.0f)))*199.f;
    float px = (nx0 + nw*((float)j*(1.0f/13.0f)))*199.f;
    float y0f = floorf(py), x0f = floorf(px);
    float wy = py-y0f, wx = px-x0f;
    int y0 = (int)y0f, x0 = (int)x0f, y1i = y0+1, x1i = x0+1;
    float v00 = (y0>=0 && y0<FM_H && x0>=0 && x0<FM_W) ? 1.f : 0.f;
    float v01 = (y0>=0 && y0<FM_H && x1i>=0 && x1i<FM_W) ? 1.f : 0.f;
    float v10 = (y1i>=0 && y1i<FM_H && x0>=0 && x0<FM_W) ? 1.f : 0.f;
    float v11 = (y1i>=0 && y1i<FM_H && x1i>=0 && x1i<FM_W) ? 1.f : 0.f;
    float w00 = (1.f-wy)*(1.f-wx)*v00, w01 = (1.f-wy)*wx*v01;
    float w10 = wy*(1.f-wx)*v10, w11 = wy*wx*v11;
    int y0c = min(max(y0,0),FM_H-1), y1c = min(max(y1i,0),FM_H-1);
    int x0c = min(max(x0,0),FM_W-1), x1c = min(max(x1i,0),FM_W-1);
    unsigned base = ((unsigned)b*FM_C + (unsigned)(cg*CH_PER_THREAD))*PLANE;
    unsigned o00 = base + (unsigned)(y0c*FM_W+x0c);
    unsigned o01 = base + (unsigned)(y0c*FM_W+x1c);
    unsigned o10 = base + (unsigned)(y1c*FM_W+x0c);
    unsigned o11 = base + (unsigned)(y1c*FM_W+x1c);
    float* outp = out + (size_t)(m*FM_C + cg*CH_PER_THREAD)*HW + ij;
#pragma unroll
    for (int k = 0; k < CH_PER_THREAD; ++k) {
        float r = fm[o00]*w00 + fm[o01]*w01 + fm[o10]*w10 + fm[o11]*w11;
        outp[0] = r;
        o00 += PLANE; o01 += PLANE; o10 += PLANE; o11 += PLANE;
        outp += HW;
    }
}

extern "C" void kernel_launch(void* const* d_in, const int* in_sizes, int n_in,
                              void* d_out, int out_size, void* d_ws, size_t ws_size,
                              hipStream_t stream) {
    const float* fm      = (const float*)d_in[0];
    const float* boxes   = (const float*)d_in[1];
    const int*   box_ind = (const int*)d_in[2];
    float* out = (float*)d_out;

    if (ws_size < WS_NEED) {
        int total = out_size / CH_PER_THREAD;
        int grid = (total + 255) / 256;
        roi_fallback_kernel<<<grid, 256, 0, stream>>>(fm, boxes, box_ind, out, total);
        return;
    }

    unsigned char* rowbin = (unsigned char*)d_ws + WS_ROWBIN;
    int*   rowrank = (int*)((char*)d_ws + WS_ROWRANK);
    int*   counts  = (int*)((char*)d_ws + WS_COUNTS);
    int*   bases   = (int*)((char*)d_ws + WS_BASES);
    uint4* recs    = (uint4*)((char*)d_ws + WS_RECS);

    k1_binscan<<<1, 1024, 0, stream>>>(boxes, box_ind, rowbin, rowrank, counts, bases);
    k2_records<<<NSAMP / 256, 256, 0, stream>>>(boxes, rowbin, rowrank, bases, recs);

    hipFuncSetAttribute((const void*)k3_main,
                        hipFuncAttributeMaxDynamicSharedMemorySize, K3_LDS);
    k3_main<<<FM_N * NOCT * 64, 512, K3_LDS, stream>>>(fm, recs, counts, bases, out);
}